// Round 14
// baseline (690.589 us; speedup 1.0000x reference)
//
#include <hip/hip_runtime.h>

#define NN 50000
#define EE 800000
#define BB 500
#define SCB 196  // ceil(NN/256) scan chunks

typedef short v8s __attribute__((ext_vector_type(8)));
typedef float v4f __attribute__((ext_vector_type(4)));

__device__ __forceinline__ float bf2f(unsigned short u) {
    union { unsigned int i; float f; } v; v.i = ((unsigned int)u) << 16; return v.f;
}
__device__ __forceinline__ unsigned short f2bf(float f) {
    union { float f; unsigned int i; } v; v.f = f;
    unsigned int x = v.i;
    unsigned int r = (x + 0x7FFFu + ((x >> 16) & 1u)) >> 16;
    return (unsigned short)r;
}

__global__ void k_sentinel(float* out, float val) {
    int i = blockIdx.x * blockDim.x + threadIdx.x;
    if (i < BB * 512) out[i] = val;
}

// counts=1 (self loops)
__global__ void k_init(int* counts) {
    int i = blockIdx.x * blockDim.x + threadIdx.x;
    if (i < NN) counts[i] = 1;
}

// fused: node featurization + all 4 weight transposes
__global__ void k_prep(const float* __restrict__ nf, const int* __restrict__ bmask,
                       const float* __restrict__ bboxW, const float* __restrict__ bboxb,
                       const float* __restrict__ membed, unsigned short* __restrict__ feat,
                       const float* __restrict__ a0, unsigned short* __restrict__ d0,
                       const float* __restrict__ a1, unsigned short* __restrict__ d1,
                       const float* __restrict__ a2, unsigned short* __restrict__ d2,
                       const float* __restrict__ a3, unsigned short* __restrict__ d3) {
    int g = blockIdx.x * blockDim.x + threadIdx.x;
    if (g < NN * 64) {
        int n = g >> 6, f = g & 63;
        float s = bboxb[f];
        for (int k = 0; k < 5; ++k) s += nf[n * 5 + k] * bboxW[k * 64 + f];
        s = fmaxf(s, 0.f);
        int bm = bmask[n]; if ((unsigned)bm > 1u) bm = 0;
        float mv = fmaxf(membed[bm * 64 + f], 0.f);
        feat[(size_t)n * 128 + f] = f2bf(s);
        feat[(size_t)n * 128 + 64 + f] = f2bf(mv);
        return;
    }
    g -= NN * 64;
    const float* in; unsigned short* out; int K, Nout, idx;
    if (g < 8192)        { in = a0; out = d0; K = 128; Nout = 64;  idx = g; }
    else if (g < 24576)  { in = a1; out = d1; K = 64;  Nout = 256; idx = g - 8192; }
    else if (g < 90112)  { in = a2; out = d2; K = 256; Nout = 256; idx = g - 24576; }
    else if (g < 155648) { in = a3; out = d3; K = 256; Nout = 256; idx = g - 90112; }
    else return;
    int k = idx / Nout, n = idx % Nout;
    out[n * K + k] = f2bf(in[idx]);
}

// MFMA GEMM, NT column tiles per block. A-stripe (64 x KT) staged once; B K-sliced (BK=64).
// ATT: per-tile attention-score epilogue (tile nt == head nt).
template <int KT, int NT, bool BR, bool ATT>
__global__ __launch_bounds__(256) void k_gemm(const unsigned short* __restrict__ A,
                                              const unsigned short* __restrict__ Bt,
                                              const float* __restrict__ bias,
                                              unsigned short* __restrict__ C, int M, int ldc,
                                              const float* __restrict__ atts, const float* __restrict__ attd,
                                              float* __restrict__ asA, float* __restrict__ adA) {
    constexpr int CH = KT / 8;       // v8s chunks per A row (full K)
    constexpr int KS = KT / 64;      // K slices for B
    __shared__ v8s As[64 * CH];
    __shared__ v8s Bs[64 * 8];
    __shared__ float ap[4][4][4][4][2];
    const int t = threadIdx.x;
    const int m0 = blockIdx.x * 64;
    for (int idx = t; idx < 64 * CH; idx += 256) {
        int m = idx / CH, kc = idx % CH;
        int row = m0 + m;
        v8s v = (v8s){0, 0, 0, 0, 0, 0, 0, 0};
        if (row < M) v = *(const v8s*)(A + (size_t)row * KT + kc * 8);
        As[m * CH + ((kc & 7) ^ (m & 7)) + (kc & ~7)] = v;
    }
    const int l = t & 63, w = t >> 6;
    const int q = l >> 4, r16 = l & 15;
    const int nloc = w * 16 + r16;
#pragma unroll
    for (int nt = 0; nt < NT; ++nt) {
        const int n0 = nt * 64;
        v4f acc[4];
#pragma unroll
        for (int i = 0; i < 4; ++i) acc[i] = (v4f){0.f, 0.f, 0.f, 0.f};
#pragma unroll
        for (int ks = 0; ks < KS; ++ks) {
            __syncthreads();  // protect Bs overwrite (and As on first pass)
            for (int idx = t; idx < 64 * 8; idx += 256) {
                int n = idx / 8, kc = idx % 8;
                Bs[n * 8 + (kc ^ (n & 7))] = *(const v8s*)(Bt + (size_t)(n0 + n) * KT + ks * 64 + kc * 8);
            }
            __syncthreads();
#pragma unroll
            for (int kt = 0; kt < 2; ++kt) {
                int kcs = kt * 4 + q;
                v8s bfr = Bs[nloc * 8 + (kcs ^ (nloc & 7))];
                int kfull = ks * 8 + kcs;
#pragma unroll
                for (int mt = 0; mt < 4; ++mt) {
                    int m = mt * 16 + r16;
                    v8s afr = As[m * CH + ((kfull & 7) ^ (m & 7)) + (kfull & ~7)];
                    acc[mt] = __builtin_amdgcn_mfma_f32_16x16x32_bf16(afr, bfr, acc[mt], 0, 0, 0);
                }
            }
        }
        const int col = n0 + nloc;
#pragma unroll
        for (int mt = 0; mt < 4; ++mt) {
#pragma unroll
            for (int r = 0; r < 4; ++r) {
                int row = m0 + mt * 16 + q * 4 + r;
                if (row < M) {
                    float v = acc[mt][r];
                    if (BR) v = fmaxf(v + bias[col], 0.f);
                    C[(size_t)row * ldc + col] = f2bf(v);
                }
            }
        }
        if (ATT) {
            float sa = atts[n0 + nloc];
            float da = attd[n0 + nloc];
            float rs[4][4], rd[4][4];
#pragma unroll
            for (int mt = 0; mt < 4; ++mt)
#pragma unroll
                for (int r = 0; r < 4; ++r) { rs[mt][r] = acc[mt][r] * sa; rd[mt][r] = acc[mt][r] * da; }
#pragma unroll
            for (int d = 1; d < 16; d <<= 1) {
#pragma unroll
                for (int mt = 0; mt < 4; ++mt)
#pragma unroll
                    for (int r = 0; r < 4; ++r) {
                        rs[mt][r] += __shfl_xor(rs[mt][r], d, 64);
                        rd[mt][r] += __shfl_xor(rd[mt][r], d, 64);
                    }
            }
            __syncthreads();  // ap reuse across nt
            if (r16 == 0) {
#pragma unroll
                for (int mt = 0; mt < 4; ++mt)
#pragma unroll
                    for (int r = 0; r < 4; ++r) { ap[w][q][mt][r][0] = rs[mt][r]; ap[w][q][mt][r][1] = rd[mt][r]; }
            }
            __syncthreads();
            if (t < 128) {
                int row = t >> 1, which = t & 1;
                int qq = (row >> 2) & 3, mtt = row >> 4, rr = row & 3;
                float s = ap[0][qq][mtt][rr][which] + ap[1][qq][mtt][rr][which] +
                          ap[2][qq][mtt][rr][which] + ap[3][qq][mtt][rr][which];
                if (m0 + row < M) (which ? adA : asA)[(m0 + row) * 4 + nt] = s;
            }
        }
    }
}

// CSR count (dst = edge_index[1])
__global__ void k_count(const int* __restrict__ dst, int* __restrict__ counts) {
    int e = blockIdx.x * blockDim.x + threadIdx.x;
    if (e < EE) {
        int d = dst[e];
        if ((unsigned)d < (unsigned)NN) atomicAdd(&counts[d], 1);
    }
}

// 3-phase parallel exclusive scan
__global__ __launch_bounds__(256) void k_scanA(const int* __restrict__ counts, int* __restrict__ bsum) {
    __shared__ int red[256];
    const int b = blockIdx.x, t = threadIdx.x;
    int i = b * 256 + t;
    red[t] = (i < NN) ? counts[i] : 0;
    __syncthreads();
    for (int d = 128; d > 0; d >>= 1) {
        if (t < d) red[t] += red[t + d];
        __syncthreads();
    }
    if (t == 0) bsum[b] = red[0];
}

__global__ __launch_bounds__(256) void k_scanB(const int* __restrict__ bsum, int* __restrict__ boff) {
    __shared__ int s[256];
    const int t = threadIdx.x;
    int v = (t < SCB) ? bsum[t] : 0;
    s[t] = v;
    __syncthreads();
    for (int d = 1; d < 256; d <<= 1) {
        int x = (t >= d) ? s[t - d] : 0;
        __syncthreads();
        s[t] += x;
        __syncthreads();
    }
    if (t < SCB) boff[t] = s[t] - v;
}

__global__ __launch_bounds__(256) void k_scanC(const int* __restrict__ counts, const int* __restrict__ boff,
                                               int* __restrict__ off, int* __restrict__ cur) {
    __shared__ int s[256];
    const int b = blockIdx.x, t = threadIdx.x;
    int i = b * 256 + t;
    int v = (i < NN) ? counts[i] : 0;
    s[t] = v;
    __syncthreads();
    for (int d = 1; d < 256; d <<= 1) {
        int x = (t >= d) ? s[t - d] : 0;
        __syncthreads();
        s[t] += x;
        __syncthreads();
    }
    int excl = s[t] - v + boff[b];
    if (i < NN) { off[i] = excl; cur[i] = excl; }
    if (i == NN - 1) off[NN] = excl + v;
}

__global__ void k_scatter(const int* __restrict__ ei, int* __restrict__ cur, int* __restrict__ csr) {
    int e = blockIdx.x * blockDim.x + threadIdx.x;
    if (e >= EE + NN) return;
    int s, d;
    if (e < EE) { s = ei[e]; d = ei[EE + e]; } else { s = e - EE; d = s; }
    if ((unsigned)d >= (unsigned)NN) return;
    if ((unsigned)s >= (unsigned)NN) s = d;
    int pos = atomicAdd(&cur[d], 1);
    csr[pos] = s;
}

// GAT two-phase softmax+aggregate: one wave per node (phase1 edge-parallel -> LDS; phase2 unrolled 8x)
__global__ __launch_bounds__(256) void k_agg(const unsigned short* __restrict__ h,
                                             const float* __restrict__ asA, const float* __restrict__ adA,
                                             const int* __restrict__ off, const int* __restrict__ csr,
                                             const float* __restrict__ bias,
                                             unsigned short* __restrict__ nout) {
    __shared__ int   sL[4][64];
    __shared__ float wL[4][64][4];
    const int nd4 = threadIdx.x >> 6;
    const int node = blockIdx.x * 4 + nd4;
    const int l = threadIdx.x & 63;
    const int hl = l >> 4, k16 = l & 15;
    const int o0 = off[node];
    const int deg = off[node + 1] - o0;
    const int dcap = deg < 64 ? deg : 64;
    const float ad4 = adA[node * 4 + hl];
    float sm = 0.f;
    for (int k = k16; k < dcap; k += 16) {
        int s = csr[o0 + k];
        if (hl == 0) sL[nd4][k] = s;
        float e = asA[s * 4 + hl] + ad4;
        e = e > 0.f ? e : 0.2f * e;
        float w = __expf(e);
        wL[nd4][k][hl] = w;
        sm += w;
    }
    for (int k = 64 + k16; k < deg; k += 16) {
        int s = csr[o0 + k];
        float e = asA[s * 4 + hl] + ad4;
        e = e > 0.f ? e : 0.2f * e;
        sm += __expf(e);
    }
#pragma unroll
    for (int d = 1; d < 16; d <<= 1) sm += __shfl_xor(sm, d, 64);
    const float rden = 1.f / sm;
    __syncthreads();
    float a0 = 0.f, a1 = 0.f, a2 = 0.f, a3 = 0.f;
    const int c = l * 4;
    int k = 0;
    for (; k + 8 <= dcap; k += 8) {
        int s0 = sL[nd4][k], s1 = sL[nd4][k + 1], s2 = sL[nd4][k + 2], s3 = sL[nd4][k + 3];
        int s4 = sL[nd4][k + 4], s5 = sL[nd4][k + 5], s6 = sL[nd4][k + 6], s7 = sL[nd4][k + 7];
        ushort4 h0 = *(const ushort4*)(h + (size_t)s0 * 256 + c);
        ushort4 h1 = *(const ushort4*)(h + (size_t)s1 * 256 + c);
        ushort4 h2 = *(const ushort4*)(h + (size_t)s2 * 256 + c);
        ushort4 h3 = *(const ushort4*)(h + (size_t)s3 * 256 + c);
        ushort4 h4 = *(const ushort4*)(h + (size_t)s4 * 256 + c);
        ushort4 h5 = *(const ushort4*)(h + (size_t)s5 * 256 + c);
        ushort4 h6 = *(const ushort4*)(h + (size_t)s6 * 256 + c);
        ushort4 h7 = *(const ushort4*)(h + (size_t)s7 * 256 + c);
        float w0 = wL[nd4][k][hl], w1 = wL[nd4][k + 1][hl], w2 = wL[nd4][k + 2][hl], w3 = wL[nd4][k + 3][hl];
        float w4 = wL[nd4][k + 4][hl], w5 = wL[nd4][k + 5][hl], w6 = wL[nd4][k + 6][hl], w7 = wL[nd4][k + 7][hl];
        a0 += w0 * bf2f(h0.x) + w1 * bf2f(h1.x) + w2 * bf2f(h2.x) + w3 * bf2f(h3.x)
            + w4 * bf2f(h4.x) + w5 * bf2f(h5.x) + w6 * bf2f(h6.x) + w7 * bf2f(h7.x);
        a1 += w0 * bf2f(h0.y) + w1 * bf2f(h1.y) + w2 * bf2f(h2.y) + w3 * bf2f(h3.y)
            + w4 * bf2f(h4.y) + w5 * bf2f(h5.y) + w6 * bf2f(h6.y) + w7 * bf2f(h7.y);
        a2 += w0 * bf2f(h0.z) + w1 * bf2f(h1.z) + w2 * bf2f(h2.z) + w3 * bf2f(h3.z)
            + w4 * bf2f(h4.z) + w5 * bf2f(h5.z) + w6 * bf2f(h6.z) + w7 * bf2f(h7.z);
        a3 += w0 * bf2f(h0.w) + w1 * bf2f(h1.w) + w2 * bf2f(h2.w) + w3 * bf2f(h3.w)
            + w4 * bf2f(h4.w) + w5 * bf2f(h5.w) + w6 * bf2f(h6.w) + w7 * bf2f(h7.w);
    }
    for (; k < dcap; ++k) {
        int s = sL[nd4][k];
        float w = wL[nd4][k][hl];
        ushort4 hv = *(const ushort4*)(h + (size_t)s * 256 + c);
        a0 += w * bf2f(hv.x); a1 += w * bf2f(hv.y); a2 += w * bf2f(hv.z); a3 += w * bf2f(hv.w);
    }
    for (int k2 = 64; k2 < deg; ++k2) {
        int s = csr[o0 + k2];
        float e = asA[s * 4 + hl] + ad4;
        e = e > 0.f ? e : 0.2f * e;
        float w = __expf(e);
        ushort4 hv = *(const ushort4*)(h + (size_t)s * 256 + c);
        a0 += w * bf2f(hv.x); a1 += w * bf2f(hv.y); a2 += w * bf2f(hv.z); a3 += w * bf2f(hv.w);
    }
    float4 bv = *(const float4*)(bias + c);
    ushort4 o;
    o.x = f2bf(fmaxf(a0 * rden + bv.x, 0.f));
    o.y = f2bf(fmaxf(a1 * rden + bv.y, 0.f));
    o.z = f2bf(fmaxf(a2 * rden + bv.z, 0.f));
    o.w = f2bf(fmaxf(a3 * rden + bv.w, 0.f));
    *(ushort4*)(nout + (size_t)node * 256 + c) = o;
}

// per-graph segment max; graph range via binary search on sorted batch
__global__ __launch_bounds__(256) void k_gmaxseg(const unsigned short* __restrict__ nt, int cols,
                                                 const int* __restrict__ batch,
                                                 float* __restrict__ gcat, int gbase) {
    __shared__ float red[256];
    const int b = blockIdx.x, t = threadIdx.x;
    int lo = 0, hi = NN;
    while (lo < hi) { int mid = (lo + hi) >> 1; if (batch[mid] < b) lo = mid + 1; else hi = mid; }
    int lo2 = lo, hi2 = NN;
    while (lo2 < hi2) { int mid = (lo2 + hi2) >> 1; if (batch[mid] < b + 1) lo2 = mid + 1; else hi2 = mid; }
    const int c = t % cols, chunk = t / cols, nch = 256 / cols;
    float m = 0.f;
    for (int n = lo + chunk; n < lo2; n += nch)
        m = fmaxf(m, bf2f(nt[(size_t)n * cols + c]));
    if (nch > 1) {
        red[t] = m;
        __syncthreads();
        if (chunk == 0)
            for (int j = 1; j < nch; ++j) m = fmaxf(m, red[j * cols + c]);
    }
    if (chunk == 0) gcat[b * 832 + gbase + c] = m;
}

// head
__global__ __launch_bounds__(256) void k_final(const float* __restrict__ gcat,
                                               const float* __restrict__ aggW, const float* __restrict__ aggb,
                                               const float* __restrict__ muW, const float* __restrict__ mub,
                                               const float* __restrict__ vaW, const float* __restrict__ vab,
                                               float* __restrict__ out) {
    __shared__ float gr[832];
    __shared__ float lat[256];
    const int b = blockIdx.x, t = threadIdx.x;
    for (int i = t; i < 832; i += 256) gr[i] = gcat[b * 832 + i];
    __syncthreads();
    float s = aggb[t];
    for (int k = 0; k < 832; ++k) s += gr[k] * aggW[k * 256 + t];
    lat[t] = s;
    __syncthreads();
    float m = mub[t], v = vab[t];
    for (int k = 0; k < 256; ++k) {
        float lk = lat[k];
        m += lk * muW[k * 256 + t];
        v += lk * vaW[k * 256 + t];
    }
    out[b * 256 + t] = m;
    out[BB * 256 + b * 256 + t] = v;
}

extern "C" void kernel_launch(void* const* d_in, const int* in_sizes, int n_in,
                              void* d_out, int out_size, void* d_ws, size_t ws_size,
                              hipStream_t stream) {
    (void)in_sizes; (void)n_in; (void)out_size;
    const float* nf     = (const float*)d_in[0];
    const int*   bmask  = (const int*)d_in[1];
    const int*   batch  = (const int*)d_in[2];
    const int*   ei     = (const int*)d_in[3];
    const float* bboxW  = (const float*)d_in[4];
    const float* bboxb  = (const float*)d_in[5];
    const float* membed = (const float*)d_in[6];
    const float* nodeW  = (const float*)d_in[7];
    const float* nodeb  = (const float*)d_in[8];
    const float* w0     = (const float*)d_in[9];
    const float* as0    = (const float*)d_in[10];
    const float* ad0    = (const float*)d_in[11];
    const float* b0     = (const float*)d_in[12];
    const float* w1     = (const float*)d_in[13];
    const float* as1    = (const float*)d_in[14];
    const float* ad1    = (const float*)d_in[15];
    const float* b1     = (const float*)d_in[16];
    const float* w2     = (const float*)d_in[17];
    const float* as2    = (const float*)d_in[18];
    const float* ad2    = (const float*)d_in[19];
    const float* b2     = (const float*)d_in[20];
    const float* aggW   = (const float*)d_in[21];
    const float* aggb   = (const float*)d_in[22];
    const float* muW    = (const float*)d_in[23];
    const float* mub    = (const float*)d_in[24];
    const float* vaW    = (const float*)d_in[25];
    const float* vab    = (const float*)d_in[26];
    float* out = (float*)d_out;

    char* base = (char*)d_ws;
    unsigned short* hbuf    = (unsigned short*)(base);
    unsigned short* nbuf    = (unsigned short*)(base + 25600000);
    unsigned short* feat128 = nbuf;                                          // overlay
    unsigned short* n0buf   = (unsigned short*)(base + 25600000 + 12800000); // overlay
    char* pool0 = base + 51200000;
    char* p = pool0;
    auto alloc = [&](size_t bytes) { char* r = p; p += (bytes + 255) & ~(size_t)255; return r; };
    unsigned short* nodeWt = (unsigned short*)alloc(128 * 64 * 2);
    unsigned short* w0t    = (unsigned short*)alloc(64 * 256 * 2);
    unsigned short* w1t    = (unsigned short*)alloc(256 * 256 * 2);
    unsigned short* w2t    = (unsigned short*)alloc(256 * 256 * 2);
    float* asA    = (float*)alloc((size_t)NN * 4 * 4);
    float* adA    = (float*)alloc((size_t)NN * 4 * 4);
    int*   counts = (int*)alloc((size_t)NN * 4);
    int*   offs   = (int*)alloc((size_t)(NN + 1) * 4);
    int*   cur    = (int*)alloc((size_t)NN * 4);
    int*   csr    = (int*)alloc((size_t)(EE + NN) * 4);
    float* gcat   = (float*)alloc((size_t)BB * 832 * 4);
    int*   bsum   = (int*)alloc(SCB * 4);
    int*   boff   = (int*)alloc(SCB * 4);
    const size_t NEED = (size_t)(p - base);

    if (ws_size < NEED) {
        k_sentinel<<<1000, 256, 0, stream>>>(out, 2000.0f + (float)(ws_size >> 20));
        return;
    }

    k_init<<<(NN + 255) / 256, 256, 0, stream>>>(counts);
    k_prep<<<(NN * 64 + 155648 + 255) / 256, 256, 0, stream>>>(nf, bmask, bboxW, bboxb, membed, feat128,
                                                               nodeW, nodeWt, w0, w0t, w1, w1t, w2, w2t);
    // CSR
    k_count<<<(EE + 255) / 256, 256, 0, stream>>>(ei + EE, counts);
    k_scanA<<<SCB, 256, 0, stream>>>(counts, bsum);
    k_scanB<<<1, 256, 0, stream>>>(bsum, boff);
    k_scanC<<<SCB, 256, 0, stream>>>(counts, boff, offs, cur);
    k_scatter<<<(EE + NN + 255) / 256, 256, 0, stream>>>(ei, cur, csr);
    // n0
    k_gemm<128, 1, true, false><<<782, 256, 0, stream>>>(feat128, nodeWt, nodeb, n0buf, NN, 64,
                                                         nullptr, nullptr, nullptr, nullptr);
    k_gmaxseg<<<BB, 256, 0, stream>>>(n0buf, 64, batch, gcat, 0);
    // layer 0
    k_gemm<64, 4, false, true><<<782, 256, 0, stream>>>(n0buf, w0t, nullptr, hbuf, NN, 256,
                                                        as0, ad0, asA, adA);
    k_agg<<<NN / 4, 256, 0, stream>>>(hbuf, asA, adA, offs, csr, b0, nbuf);
    k_gmaxseg<<<BB, 256, 0, stream>>>(nbuf, 256, batch, gcat, 64);
    // layer 1
    k_gemm<256, 4, false, true><<<782, 256, 0, stream>>>(nbuf, w1t, nullptr, hbuf, NN, 256,
                                                         as1, ad1, asA, adA);
    k_agg<<<NN / 4, 256, 0, stream>>>(hbuf, asA, adA, offs, csr, b1, nbuf);
    k_gmaxseg<<<BB, 256, 0, stream>>>(nbuf, 256, batch, gcat, 320);
    // layer 2
    k_gemm<256, 4, false, true><<<782, 256, 0, stream>>>(nbuf, w2t, nullptr, hbuf, NN, 256,
                                                         as2, ad2, asA, adA);
    k_agg<<<NN / 4, 256, 0, stream>>>(hbuf, asA, adA, offs, csr, b2, nbuf);
    k_gmaxseg<<<BB, 256, 0, stream>>>(nbuf, 256, batch, gcat, 576);
    // head
    k_final<<<BB, 256, 0, stream>>>(gcat, aggW, aggb, muW, mub, vaW, vab, out);
}

// Round 15
// 676.325 us; speedup vs baseline: 1.0211x; 1.0211x over previous
//
#include <hip/hip_runtime.h>

#define NN 50000
#define EE 800000
#define BB 500
#define SCB 196  // ceil(NN/256) scan chunks

typedef short v8s __attribute__((ext_vector_type(8)));
typedef float v4f __attribute__((ext_vector_type(4)));

__device__ __forceinline__ float bf2f(unsigned short u) {
    union { unsigned int i; float f; } v; v.i = ((unsigned int)u) << 16; return v.f;
}
__device__ __forceinline__ unsigned short f2bf(float f) {
    union { float f; unsigned int i; } v; v.f = f;
    unsigned int x = v.i;
    unsigned int r = (x + 0x7FFFu + ((x >> 16) & 1u)) >> 16;
    return (unsigned short)r;
}

__global__ void k_sentinel(float* out, float val) {
    int i = blockIdx.x * blockDim.x + threadIdx.x;
    if (i < BB * 512) out[i] = val;
}

// fused: counts init + node featurization + all 4 weight transposes
__global__ void k_prep(const float* __restrict__ nf, const int* __restrict__ bmask,
                       const float* __restrict__ bboxW, const float* __restrict__ bboxb,
                       const float* __restrict__ membed, unsigned short* __restrict__ feat,
                       const float* __restrict__ a0, unsigned short* __restrict__ d0,
                       const float* __restrict__ a1, unsigned short* __restrict__ d1,
                       const float* __restrict__ a2, unsigned short* __restrict__ d2,
                       const float* __restrict__ a3, unsigned short* __restrict__ d3,
                       int* __restrict__ counts) {
    int g = blockIdx.x * blockDim.x + threadIdx.x;
    if (g < NN) counts[g] = 1;
    if (g < NN * 64) {
        int n = g >> 6, f = g & 63;
        float s = bboxb[f];
        for (int k = 0; k < 5; ++k) s += nf[n * 5 + k] * bboxW[k * 64 + f];
        s = fmaxf(s, 0.f);
        int bm = bmask[n]; if ((unsigned)bm > 1u) bm = 0;
        float mv = fmaxf(membed[bm * 64 + f], 0.f);
        feat[(size_t)n * 128 + f] = f2bf(s);
        feat[(size_t)n * 128 + 64 + f] = f2bf(mv);
        return;
    }
    g -= NN * 64;
    const float* in; unsigned short* out; int K, Nout, idx;
    if (g < 8192)        { in = a0; out = d0; K = 128; Nout = 64;  idx = g; }
    else if (g < 24576)  { in = a1; out = d1; K = 64;  Nout = 256; idx = g - 8192; }
    else if (g < 90112)  { in = a2; out = d2; K = 256; Nout = 256; idx = g - 24576; }
    else if (g < 155648) { in = a3; out = d3; K = 256; Nout = 256; idx = g - 90112; }
    else return;
    int k = idx / Nout, n = idx % Nout;
    out[n * K + k] = f2bf(in[idx]);
}

// MFMA GEMM (round-13 shape: full-K LDS, 2 barriers; block (bx,by) owns col tile by)
// ATT: fused attention-score epilogue (tile by == head by)
template <int KT, bool BR, bool ATT>
__global__ __launch_bounds__(256) void k_gemm(const unsigned short* __restrict__ A,
                                              const unsigned short* __restrict__ Bt,
                                              const float* __restrict__ bias,
                                              unsigned short* __restrict__ C, int M, int ldc,
                                              const float* __restrict__ atts, const float* __restrict__ attd,
                                              float* __restrict__ asA, float* __restrict__ adA) {
    constexpr int CH = KT / 8;
    __shared__ v8s As[64 * CH];
    __shared__ v8s Bs[64 * CH];
    __shared__ float ap[4][4][4][4][2];
    const int t = threadIdx.x;
    const int m0 = blockIdx.x * 64;
    const int n0 = blockIdx.y * 64;
    for (int idx = t; idx < 64 * CH; idx += 256) {
        int m = idx / CH, kc = idx % CH;
        int row = m0 + m;
        v8s v = (v8s){0, 0, 0, 0, 0, 0, 0, 0};
        if (row < M) v = *(const v8s*)(A + (size_t)row * KT + kc * 8);
        As[m * CH + (kc ^ (m & 7))] = v;
    }
    for (int idx = t; idx < 64 * CH; idx += 256) {
        int n = idx / CH, kc = idx % CH;
        v8s v = *(const v8s*)(Bt + (size_t)(n0 + n) * KT + kc * 8);
        Bs[n * CH + (kc ^ (n & 7))] = v;
    }
    __syncthreads();
    const int l = t & 63, w = t >> 6;
    const int q = l >> 4, r16 = l & 15;
    const int nloc = w * 16 + r16;
    v4f acc[4];
#pragma unroll
    for (int i = 0; i < 4; ++i) acc[i] = (v4f){0.f, 0.f, 0.f, 0.f};
#pragma unroll
    for (int kt = 0; kt < KT / 32; ++kt) {
        int kc = kt * 4 + q;
        v8s bfr = Bs[nloc * CH + (kc ^ (nloc & 7))];
#pragma unroll
        for (int mt = 0; mt < 4; ++mt) {
            v8s afr = As[(mt * 16 + r16) * CH + (kc ^ (r16 & 7))];
            acc[mt] = __builtin_amdgcn_mfma_f32_16x16x32_bf16(afr, bfr, acc[mt], 0, 0, 0);
        }
    }
    const int col = n0 + nloc;
#pragma unroll
    for (int mt = 0; mt < 4; ++mt) {
#pragma unroll
        for (int r = 0; r < 4; ++r) {
            int row = m0 + mt * 16 + q * 4 + r;
            if (row < M) {
                float v = acc[mt][r];
                if (BR) v = fmaxf(v + bias[col], 0.f);
                C[(size_t)row * ldc + col] = f2bf(v);
            }
        }
    }
    if (ATT) {
        float sa = atts[blockIdx.y * 64 + nloc];
        float da = attd[blockIdx.y * 64 + nloc];
        float rs[4][4], rd[4][4];
#pragma unroll
        for (int mt = 0; mt < 4; ++mt)
#pragma unroll
            for (int r = 0; r < 4; ++r) { rs[mt][r] = acc[mt][r] * sa; rd[mt][r] = acc[mt][r] * da; }
#pragma unroll
        for (int d = 1; d < 16; d <<= 1) {
#pragma unroll
            for (int mt = 0; mt < 4; ++mt)
#pragma unroll
                for (int r = 0; r < 4; ++r) {
                    rs[mt][r] += __shfl_xor(rs[mt][r], d, 64);
                    rd[mt][r] += __shfl_xor(rd[mt][r], d, 64);
                }
        }
        if (r16 == 0) {
#pragma unroll
            for (int mt = 0; mt < 4; ++mt)
#pragma unroll
                for (int r = 0; r < 4; ++r) { ap[w][q][mt][r][0] = rs[mt][r]; ap[w][q][mt][r][1] = rd[mt][r]; }
        }
        __syncthreads();
        if (t < 128) {
            int row = t >> 1, which = t & 1;
            int qq = (row >> 2) & 3, mtt = row >> 4, rr = row & 3;
            float s = ap[0][qq][mtt][rr][which] + ap[1][qq][mtt][rr][which] +
                      ap[2][qq][mtt][rr][which] + ap[3][qq][mtt][rr][which];
            if (m0 + row < M) (which ? adA : asA)[(m0 + row) * 4 + blockIdx.y] = s;
        }
    }
}

// CSR count (dst = edge_index[1])
__global__ void k_count(const int* __restrict__ dst, int* __restrict__ counts) {
    int e = blockIdx.x * blockDim.x + threadIdx.x;
    if (e < EE) {
        int d = dst[e];
        if ((unsigned)d < (unsigned)NN) atomicAdd(&counts[d], 1);
    }
}

// 3-phase parallel exclusive scan
__global__ __launch_bounds__(256) void k_scanA(const int* __restrict__ counts, int* __restrict__ bsum) {
    __shared__ int red[256];
    const int b = blockIdx.x, t = threadIdx.x;
    int i = b * 256 + t;
    red[t] = (i < NN) ? counts[i] : 0;
    __syncthreads();
    for (int d = 128; d > 0; d >>= 1) {
        if (t < d) red[t] += red[t + d];
        __syncthreads();
    }
    if (t == 0) bsum[b] = red[0];
}

__global__ __launch_bounds__(256) void k_scanB(const int* __restrict__ bsum, int* __restrict__ boff) {
    __shared__ int s[256];
    const int t = threadIdx.x;
    int v = (t < SCB) ? bsum[t] : 0;
    s[t] = v;
    __syncthreads();
    for (int d = 1; d < 256; d <<= 1) {
        int x = (t >= d) ? s[t - d] : 0;
        __syncthreads();
        s[t] += x;
        __syncthreads();
    }
    if (t < SCB) boff[t] = s[t] - v;
}

__global__ __launch_bounds__(256) void k_scanC(const int* __restrict__ counts, const int* __restrict__ boff,
                                               int* __restrict__ off, int* __restrict__ cur) {
    __shared__ int s[256];
    const int b = blockIdx.x, t = threadIdx.x;
    int i = b * 256 + t;
    int v = (i < NN) ? counts[i] : 0;
    s[t] = v;
    __syncthreads();
    for (int d = 1; d < 256; d <<= 1) {
        int x = (t >= d) ? s[t - d] : 0;
        __syncthreads();
        s[t] += x;
        __syncthreads();
    }
    int excl = s[t] - v + boff[b];
    if (i < NN) { off[i] = excl; cur[i] = excl; }
    if (i == NN - 1) off[NN] = excl + v;
}

__global__ void k_scatter(const int* __restrict__ ei, int* __restrict__ cur, int* __restrict__ csr) {
    int e = blockIdx.x * blockDim.x + threadIdx.x;
    if (e >= EE + NN) return;
    int s, d;
    if (e < EE) { s = ei[e]; d = ei[EE + e]; } else { s = e - EE; d = s; }
    if ((unsigned)d >= (unsigned)NN) return;
    if ((unsigned)s >= (unsigned)NN) s = d;
    int pos = atomicAdd(&cur[d], 1);
    csr[pos] = s;
}

// GAT two-phase softmax+aggregate: one wave per node; node range [base, base+grid*4)
__global__ __launch_bounds__(256) void k_agg(const unsigned short* __restrict__ h,
                                             const float* __restrict__ asA, const float* __restrict__ adA,
                                             const int* __restrict__ off, const int* __restrict__ csr,
                                             const float* __restrict__ bias,
                                             unsigned short* __restrict__ nout, int base) {
    __shared__ int   sL[4][64];
    __shared__ float wL[4][64][4];
    const int nd4 = threadIdx.x >> 6;
    const int node = base + blockIdx.x * 4 + nd4;
    const int l = threadIdx.x & 63;
    const int hl = l >> 4, k16 = l & 15;
    const int o0 = off[node];
    const int deg = off[node + 1] - o0;
    const int dcap = deg < 64 ? deg : 64;
    const float ad4 = adA[node * 4 + hl];
    float sm = 0.f;
    for (int k = k16; k < dcap; k += 16) {
        int s = csr[o0 + k];
        if (hl == 0) sL[nd4][k] = s;
        float e = asA[s * 4 + hl] + ad4;
        e = e > 0.f ? e : 0.2f * e;
        float w = __expf(e);
        wL[nd4][k][hl] = w;
        sm += w;
    }
    for (int k = 64 + k16; k < deg; k += 16) {
        int s = csr[o0 + k];
        float e = asA[s * 4 + hl] + ad4;
        e = e > 0.f ? e : 0.2f * e;
        sm += __expf(e);
    }
#pragma unroll
    for (int d = 1; d < 16; d <<= 1) sm += __shfl_xor(sm, d, 64);
    const float rden = 1.f / sm;
    __syncthreads();
    float a0 = 0.f, a1 = 0.f, a2 = 0.f, a3 = 0.f;
    const int c = l * 4;
    int k = 0;
    for (; k + 4 <= dcap; k += 4) {
        int s0 = sL[nd4][k], s1 = sL[nd4][k + 1], s2 = sL[nd4][k + 2], s3 = sL[nd4][k + 3];
        float w0 = wL[nd4][k][hl], w1 = wL[nd4][k + 1][hl], w2 = wL[nd4][k + 2][hl], w3 = wL[nd4][k + 3][hl];
        ushort4 h0 = *(const ushort4*)(h + (size_t)s0 * 256 + c);
        ushort4 h1 = *(const ushort4*)(h + (size_t)s1 * 256 + c);
        ushort4 h2 = *(const ushort4*)(h + (size_t)s2 * 256 + c);
        ushort4 h3 = *(const ushort4*)(h + (size_t)s3 * 256 + c);
        a0 += w0 * bf2f(h0.x) + w1 * bf2f(h1.x) + w2 * bf2f(h2.x) + w3 * bf2f(h3.x);
        a1 += w0 * bf2f(h0.y) + w1 * bf2f(h1.y) + w2 * bf2f(h2.y) + w3 * bf2f(h3.y);
        a2 += w0 * bf2f(h0.z) + w1 * bf2f(h1.z) + w2 * bf2f(h2.z) + w3 * bf2f(h3.z);
        a3 += w0 * bf2f(h0.w) + w1 * bf2f(h1.w) + w2 * bf2f(h2.w) + w3 * bf2f(h3.w);
    }
    for (; k < dcap; ++k) {
        int s = sL[nd4][k];
        float w = wL[nd4][k][hl];
        ushort4 hv = *(const ushort4*)(h + (size_t)s * 256 + c);
        a0 += w * bf2f(hv.x); a1 += w * bf2f(hv.y); a2 += w * bf2f(hv.z); a3 += w * bf2f(hv.w);
    }
    for (int k2 = 64; k2 < deg; ++k2) {
        int s = csr[o0 + k2];
        float e = asA[s * 4 + hl] + ad4;
        e = e > 0.f ? e : 0.2f * e;
        float w = __expf(e);
        ushort4 hv = *(const ushort4*)(h + (size_t)s * 256 + c);
        a0 += w * bf2f(hv.x); a1 += w * bf2f(hv.y); a2 += w * bf2f(hv.z); a3 += w * bf2f(hv.w);
    }
    float4 bv = *(const float4*)(bias + c);
    ushort4 o;
    o.x = f2bf(fmaxf(a0 * rden + bv.x, 0.f));
    o.y = f2bf(fmaxf(a1 * rden + bv.y, 0.f));
    o.z = f2bf(fmaxf(a2 * rden + bv.z, 0.f));
    o.w = f2bf(fmaxf(a3 * rden + bv.w, 0.f));
    *(ushort4*)(nout + (size_t)node * 256 + c) = o;
}

// per-graph segment max, 2-D grid (graph, 64-col group); 256 thr = 4 row chunks x 64 cols
__global__ __launch_bounds__(256) void k_gmaxseg(const unsigned short* __restrict__ nt, int cols,
                                                 const int* __restrict__ batch,
                                                 float* __restrict__ gcat, int gbase) {
    __shared__ float red[256];
    const int b = blockIdx.x, t = threadIdx.x;
    const int lane = t & 63, chunk = t >> 6;
    const int c = blockIdx.y * 64 + lane;
    int lo = 0, hi = NN;
    while (lo < hi) { int mid = (lo + hi) >> 1; if (batch[mid] < b) lo = mid + 1; else hi = mid; }
    int lo2 = lo, hi2 = NN;
    while (lo2 < hi2) { int mid = (lo2 + hi2) >> 1; if (batch[mid] < b + 1) lo2 = mid + 1; else hi2 = mid; }
    float m = 0.f;
    for (int n = lo + chunk; n < lo2; n += 4)
        m = fmaxf(m, bf2f(nt[(size_t)n * cols + c]));
    red[t] = m;
    __syncthreads();
    if (chunk == 0) {
        m = fmaxf(fmaxf(m, red[64 + lane]), fmaxf(red[128 + lane], red[192 + lane]));
        gcat[b * 832 + gbase + c] = m;
    }
}

// head: 4 graphs per block (125 blocks) — weights read once, used 4x
__global__ __launch_bounds__(256) void k_final(const float* __restrict__ gcat,
                                               const float* __restrict__ aggW, const float* __restrict__ aggb,
                                               const float* __restrict__ muW, const float* __restrict__ mub,
                                               const float* __restrict__ vaW, const float* __restrict__ vab,
                                               float* __restrict__ out) {
    __shared__ float gr[4][832];
    __shared__ float lat[4][256];
    const int b0 = blockIdx.x * 4, t = threadIdx.x;
    for (int i = t; i < 4 * 832; i += 256) gr[i / 832][i % 832] = gcat[b0 * 832 + i];
    __syncthreads();
    float s0 = aggb[t], s1 = s0, s2 = s0, s3 = s0;
    for (int k = 0; k < 832; ++k) {
        float wv = aggW[k * 256 + t];
        s0 += gr[0][k] * wv; s1 += gr[1][k] * wv; s2 += gr[2][k] * wv; s3 += gr[3][k] * wv;
    }
    lat[0][t] = s0; lat[1][t] = s1; lat[2][t] = s2; lat[3][t] = s3;
    __syncthreads();
    float m0 = mub[t], m1 = m0, m2 = m0, m3 = m0;
    float v0 = vab[t], v1 = v0, v2 = v0, v3 = v0;
    for (int k = 0; k < 256; ++k) {
        float wm = muW[k * 256 + t], wv = vaW[k * 256 + t];
        float l0 = lat[0][k], l1 = lat[1][k], l2 = lat[2][k], l3 = lat[3][k];
        m0 += l0 * wm; m1 += l1 * wm; m2 += l2 * wm; m3 += l3 * wm;
        v0 += l0 * wv; v1 += l1 * wv; v2 += l2 * wv; v3 += l3 * wv;
    }
    out[(b0 + 0) * 256 + t] = m0;
    out[(b0 + 1) * 256 + t] = m1;
    out[(b0 + 2) * 256 + t] = m2;
    out[(b0 + 3) * 256 + t] = m3;
    out[BB * 256 + (b0 + 0) * 256 + t] = v0;
    out[BB * 256 + (b0 + 1) * 256 + t] = v1;
    out[BB * 256 + (b0 + 2) * 256 + t] = v2;
    out[BB * 256 + (b0 + 3) * 256 + t] = v3;
}

extern "C" void kernel_launch(void* const* d_in, const int* in_sizes, int n_in,
                              void* d_out, int out_size, void* d_ws, size_t ws_size,
                              hipStream_t stream) {
    (void)in_sizes; (void)n_in; (void)out_size;
    const float* nf     = (const float*)d_in[0];
    const int*   bmask  = (const int*)d_in[1];
    const int*   batch  = (const int*)d_in[2];
    const int*   ei     = (const int*)d_in[3];
    const float* bboxW  = (const float*)d_in[4];
    const float* bboxb  = (const float*)d_in[5];
    const float* membed = (const float*)d_in[6];
    const float* nodeW  = (const float*)d_in[7];
    const float* nodeb  = (const float*)d_in[8];
    const float* w0     = (const float*)d_in[9];
    const float* as0    = (const float*)d_in[10];
    const float* ad0    = (const float*)d_in[11];
    const float* b0     = (const float*)d_in[12];
    const float* w1     = (const float*)d_in[13];
    const float* as1    = (const float*)d_in[14];
    const float* ad1    = (const float*)d_in[15];
    const float* b1     = (const float*)d_in[16];
    const float* w2     = (const float*)d_in[17];
    const float* as2    = (const float*)d_in[18];
    const float* ad2    = (const float*)d_in[19];
    const float* b2     = (const float*)d_in[20];
    const float* aggW   = (const float*)d_in[21];
    const float* aggb   = (const float*)d_in[22];
    const float* muW    = (const float*)d_in[23];
    const float* mub    = (const float*)d_in[24];
    const float* vaW    = (const float*)d_in[25];
    const float* vab    = (const float*)d_in[26];
    float* out = (float*)d_out;

    char* base = (char*)d_ws;
    unsigned short* hbuf    = (unsigned short*)(base);
    unsigned short* nbuf    = (unsigned short*)(base + 25600000);
    unsigned short* feat128 = nbuf;                                          // overlay
    unsigned short* n0buf   = (unsigned short*)(base + 25600000 + 12800000); // overlay
    char* pool0 = base + 51200000;
    char* p = pool0;
    auto alloc = [&](size_t bytes) { char* r = p; p += (bytes + 255) & ~(size_t)255; return r; };
    unsigned short* nodeWt = (unsigned short*)alloc(128 * 64 * 2);
    unsigned short* w0t    = (unsigned short*)alloc(64 * 256 * 2);
    unsigned short* w1t    = (unsigned short*)alloc(256 * 256 * 2);
    unsigned short* w2t    = (unsigned short*)alloc(256 * 256 * 2);
    float* asA    = (float*)alloc((size_t)NN * 4 * 4);
    float* adA    = (float*)alloc((size_t)NN * 4 * 4);
    int*   counts = (int*)alloc((size_t)NN * 4);
    int*   offs   = (int*)alloc((size_t)(NN + 1) * 4);
    int*   cur    = (int*)alloc((size_t)NN * 4);
    int*   csr    = (int*)alloc((size_t)(EE + NN) * 4);
    float* gcat   = (float*)alloc((size_t)BB * 832 * 4);
    int*   bsum   = (int*)alloc(SCB * 4);
    int*   boff   = (int*)alloc(SCB * 4);
    const size_t NEED = (size_t)(p - base);

    if (ws_size < NEED) {
        k_sentinel<<<1000, 256, 0, stream>>>(out, 2000.0f + (float)(ws_size >> 20));
        return;
    }

    k_prep<<<(NN * 64 + 155648 + 255) / 256, 256, 0, stream>>>(nf, bmask, bboxW, bboxb, membed, feat128,
                                                               nodeW, nodeWt, w0, w0t, w1, w1t, w2, w2t, counts);
    // CSR
    k_count<<<(EE + 255) / 256, 256, 0, stream>>>(ei + EE, counts);
    k_scanA<<<SCB, 256, 0, stream>>>(counts, bsum);
    k_scanB<<<1, 256, 0, stream>>>(bsum, boff);
    k_scanC<<<SCB, 256, 0, stream>>>(counts, boff, offs, cur);
    k_scatter<<<(EE + NN + 255) / 256, 256, 0, stream>>>(ei, cur, csr);
    // n0
    k_gemm<128, true, false><<<dim3(782, 1), 256, 0, stream>>>(feat128, nodeWt, nodeb, n0buf, NN, 64,
                                                               nullptr, nullptr, nullptr, nullptr);
    k_gmaxseg<<<dim3(BB, 1), 256, 0, stream>>>(n0buf, 64, batch, gcat, 0);
    // layer 0
    k_gemm<64, false, true><<<dim3(782, 4), 256, 0, stream>>>(n0buf, w0t, nullptr, hbuf, NN, 256,
                                                              as0, ad0, asA, adA);
    k_agg<<<6250, 256, 0, stream>>>(hbuf, asA, adA, offs, csr, b0, nbuf, 0);
    k_agg<<<6250, 256, 0, stream>>>(hbuf, asA, adA, offs, csr, b0, nbuf, 25000);
    k_gmaxseg<<<dim3(BB, 4), 256, 0, stream>>>(nbuf, 256, batch, gcat, 64);
    // layer 1
    k_gemm<256, false, true><<<dim3(782, 4), 256, 0, stream>>>(nbuf, w1t, nullptr, hbuf, NN, 256,
                                                               as1, ad1, asA, adA);
    k_agg<<<6250, 256, 0, stream>>>(hbuf, asA, adA, offs, csr, b1, nbuf, 0);
    k_agg<<<6250, 256, 0, stream>>>(hbuf, asA, adA, offs, csr, b1, nbuf, 25000);
    k_gmaxseg<<<dim3(BB, 4), 256, 0, stream>>>(nbuf, 256, batch, gcat, 320);
    // layer 2
    k_gemm<256, false, true><<<dim3(782, 4), 256, 0, stream>>>(nbuf, w2t, nullptr, hbuf, NN, 256,
                                                               as2, ad2, asA, adA);
    k_agg<<<6250, 256, 0, stream>>>(hbuf, asA, adA, offs, csr, b2, nbuf, 0);
    k_agg<<<6250, 256, 0, stream>>>(hbuf, asA, adA, offs, csr, b2, nbuf, 25000);
    k_gmaxseg<<<dim3(BB, 4), 256, 0, stream>>>(nbuf, 256, batch, gcat, 576);
    // head (4 graphs/block)
    k_final<<<BB / 4, 256, 0, stream>>>(gcat, aggW, aggb, muW, mub, vaW, vab, out);
}